// Round 4
// baseline (1652.687 us; speedup 1.0000x reference)
//
#include <hip/hip_runtime.h>

#define BB 512
#define TT 1024
#define DD 64
#define HH 32
#define CC 4

typedef float f4 __attribute__((ext_vector_type(4)));

__device__ __forceinline__ float rcpf(float x) { return __builtin_amdgcn_rcpf(x); }
__device__ __forceinline__ float sigm(float x) { return rcpf(1.0f + __expf(-x)); }
__device__ __forceinline__ float tanh_f(float x) {
    return 1.0f - 2.0f * rcpf(__expf(2.0f * x) + 1.0f);
}

// ---------------- Kernel 1: zx[b,t,r] = bias0[r] + sum_k x[b,t,k]*w_ih0[r,k] ----------
// block = (tile of 16 timesteps) x (one batch b); 128 threads, thread = gate row r.
__global__ void __launch_bounds__(128, 4)
zx_gemm(const float* __restrict__ states,  // [B,T,64]
        const float* __restrict__ w_ih0,   // [128,68]
        const float* __restrict__ b_ih0,
        const float* __restrict__ b_hh0,
        float* __restrict__ zx,            // [B,Tc,128]
        int t0, int tc, int Tc)
{
    const int b = blockIdx.y;
    const int tile = blockIdx.x;
    const int tid = threadIdx.x;
    __shared__ __align__(16) float xs[16][DD];

    const int tbase = t0 + tile * 16;
#pragma unroll
    for (int i = 0; i < 2; ++i) {
        int f = i * 128 + tid;           // float4 id 0..255
        int row = f >> 4, c4 = f & 15;
        int t = tbase + row; if (t > TT - 1) t = TT - 1;
        ((f4*)xs)[f] = *(const f4*)(states + ((size_t)b * TT + t) * DD + c4 * 4);
    }
    __syncthreads();

    const int r = tid;
    const f4* wr = (const f4*)(w_ih0 + (size_t)r * 68);   // row is 272B = 17 f4, aligned
    f4 w[16];
#pragma unroll
    for (int k = 0; k < 16; ++k) w[k] = wr[k];
    const float bias = b_ih0[r] + b_hh0[r];

    for (int i = 0; i < 16; ++i) {
        int tloc = tile * 16 + i;
        if (tloc >= tc) break;
        const f4* xv = (const f4*)xs[i];
        float a0 = bias, a1 = 0.f, a2 = 0.f, a3 = 0.f;
#pragma unroll
        for (int k = 0; k < 16; ++k) {
            f4 x4 = xv[k];
            a0 = fmaf(w[k].x, x4.x, a0);
            a1 = fmaf(w[k].y, x4.y, a1);
            a2 = fmaf(w[k].z, x4.z, a2);
            a3 = fmaf(w[k].w, x4.w, a3);
        }
        zx[((size_t)b * Tc + tloc) * 128 + r] = (a0 + a1) + (a2 + a3);
    }
}

// ---------------- Kernel 2: the recurrence (x-projection pre-hoisted) ----------------
// 128 threads = 2 waves; lane l = g*16+u0; wave wv owns units [wv*16, wv*16+16).
// Per-thread weights: wct(4) + wh0(32) + wi1(32) + wh1(32) = 100 floats, pinned in VGPRs.
__global__ void __launch_bounds__(128, 1)
lstm_rec(const float* __restrict__ zx,      // [B,Tc,128]
         const float* __restrict__ taup,
         const float* __restrict__ gumbel,  // [T,B,1,C]
         const float* __restrict__ w_ih0,   // [128,68] (ct cols 64..67)
         const float* __restrict__ w_hh0,   // [128,32]
         const float* __restrict__ w_ih1,   // [128,32]
         const float* __restrict__ w_hh1,   // [128,32]
         const float* __restrict__ b_ih1,
         const float* __restrict__ b_hh1,
         const float* __restrict__ w_lin,   // [4,32]
         const float* __restrict__ b_lin,   // [4]
         float* __restrict__ out,           // [B,T,4]
         float* __restrict__ state,         // [B,136]
         int t0, int tc, int Tc, int first)
{
    const int b   = blockIdx.x;
    const int tid = threadIdx.x;
    const int l   = tid & 63;
    const int wv  = tid >> 6;
    const int u0  = l & 15;
    const int g   = l >> 4;
    const int u   = wv * 16 + u0;
    const int r   = g * 32 + u;

    __shared__ __align__(16) float h1b[2][HH];
    __shared__ __align__(16) float h2b[2][HH];

    // weights -> registers, then pin so the compiler can't re-load in the loop
    f4 wct = *(const f4*)(w_ih0 + (size_t)r * 68 + 64);
    f4 wh0[8], wi1[8], wh1[8];
#pragma unroll
    for (int k = 0; k < 8; ++k) wh0[k] = *(const f4*)(w_hh0 + (size_t)r * HH + 4 * k);
#pragma unroll
    for (int k = 0; k < 8; ++k) wi1[k] = *(const f4*)(w_ih1 + (size_t)r * HH + 4 * k);
#pragma unroll
    for (int k = 0; k < 8; ++k) wh1[k] = *(const f4*)(w_hh1 + (size_t)r * HH + 4 * k);
    asm volatile("" : "+v"(wh0[0]), "+v"(wh0[1]), "+v"(wh0[2]), "+v"(wh0[3]),
                      "+v"(wh0[4]), "+v"(wh0[5]), "+v"(wh0[6]), "+v"(wh0[7]));
    asm volatile("" : "+v"(wi1[0]), "+v"(wi1[1]), "+v"(wi1[2]), "+v"(wi1[3]),
                      "+v"(wi1[4]), "+v"(wi1[5]), "+v"(wi1[6]), "+v"(wi1[7]));
    asm volatile("" : "+v"(wh1[0]), "+v"(wh1[1]), "+v"(wh1[2]), "+v"(wh1[3]),
                      "+v"(wh1[4]), "+v"(wh1[5]), "+v"(wh1[6]), "+v"(wh1[7]));
    asm volatile("" : "+v"(wct));

    const float bias1 = b_ih1[r] + b_hh1[r];
    const float inv_tau = rcpf(taup[0]);
    const float wl0 = w_lin[g * HH + u0];
    const float wl1 = w_lin[g * HH + u0 + 16];
    const float blc = b_lin[g];

    float* st = state + (size_t)b * 136;
    float cst1, cst2, y0, y1, y2, y3;
    if (first) {
        cst1 = 0.f; cst2 = 0.f; y0 = 1.f; y1 = 0.f; y2 = 0.f; y3 = 0.f;
        if (tid < HH) { h1b[0][tid] = 0.f; h2b[0][tid] = 0.f; }
    } else {
        cst1 = st[32 + u]; cst2 = st[96 + u];
        y0 = st[128]; y1 = st[129]; y2 = st[130]; y3 = st[131];
        if (tid < HH) { h1b[0][tid] = st[tid]; h2b[0][tid] = st[64 + tid]; }
    }
    __syncthreads();

    const float* __restrict__ zb = zx + (size_t)b * Tc * 128;
    float* __restrict__ ob = out + (size_t)b * TT * CC;

    float zr0 = zb[r];
    float zr1 = (tc > 1) ? zb[128 + r] : zr0;

    for (int tl = 0; tl < tc; ++tl) {
        const int p = tl & 1, np = p ^ 1;
        const int tg = t0 + tl;
        const float4 gt = *(const float4*)(gumbel + ((size_t)tg * BB + b) * CC);
        float zcur = zr0;
        zr0 = zr1;
        const int tpf = (tl + 2 < tc) ? tl + 2 : tc - 1;
        zr1 = zb[(size_t)tpf * 128 + r];

        // ---- layer 0: z = zx + wct.y(ct) + wh0.h1 ----
        float a0 = zcur, a1 = 0.f, a2 = 0.f, a3 = 0.f;
        a0 = fmaf(wct.x, y0, a0);
        a1 = fmaf(wct.y, y1, a1);
        a2 = fmaf(wct.z, y2, a2);
        a3 = fmaf(wct.w, y3, a3);
        const float4* h1v = (const float4*)h1b[p];
#pragma unroll
        for (int k = 0; k < 8; ++k) {
            float4 h4 = h1v[k];
            a0 = fmaf(wh0[k].x, h4.x, a0);
            a1 = fmaf(wh0[k].y, h4.y, a1);
            a2 = fmaf(wh0[k].z, h4.z, a2);
            a3 = fmaf(wh0[k].w, h4.w, a3);
        }
        float z = (a0 + a1) + (a2 + a3);

        float v1  = __shfl_xor(z, 16, 64);
        float lo  = (g & 1) ? v1 : z;
        float hi  = (g & 1) ? z  : v1;
        float lo2 = __shfl_xor(lo, 32, 64);
        float hi2 = __shfl_xor(hi, 32, 64);
        float zi = (g < 2) ? lo  : lo2;
        float zf = (g < 2) ? hi  : hi2;
        float zg = (g < 2) ? lo2 : lo;
        float zo = (g < 2) ? hi2 : hi;
        cst1 = sigm(zf) * cst1 + sigm(zi) * tanh_f(zg);
        float h1new = sigm(zo) * tanh_f(cst1);
        if (g == 0) h1b[np][u] = h1new;
        __syncthreads();                                  // h1_t visible

        // ---- layer 1 ----
        a0 = bias1; a1 = 0.f; a2 = 0.f; a3 = 0.f;
        const float4* h1n = (const float4*)h1b[np];
        const float4* h2v = (const float4*)h2b[p];
#pragma unroll
        for (int k = 0; k < 8; ++k) {
            float4 h4 = h1n[k];
            float4 g4 = h2v[k];
            a0 = fmaf(wi1[k].x, h4.x, a0);
            a1 = fmaf(wi1[k].y, h4.y, a1);
            a2 = fmaf(wi1[k].z, h4.z, a2);
            a3 = fmaf(wi1[k].w, h4.w, a3);
            a0 = fmaf(wh1[k].x, g4.x, a0);
            a1 = fmaf(wh1[k].y, g4.y, a1);
            a2 = fmaf(wh1[k].z, g4.z, a2);
            a3 = fmaf(wh1[k].w, g4.w, a3);
        }
        z = (a0 + a1) + (a2 + a3);
        v1  = __shfl_xor(z, 16, 64);
        lo  = (g & 1) ? v1 : z;
        hi  = (g & 1) ? z  : v1;
        lo2 = __shfl_xor(lo, 32, 64);
        hi2 = __shfl_xor(hi, 32, 64);
        zi = (g < 2) ? lo  : lo2;
        zf = (g < 2) ? hi  : hi2;
        zg = (g < 2) ? lo2 : lo;
        zo = (g < 2) ? hi2 : hi;
        cst2 = sigm(zf) * cst2 + sigm(zi) * tanh_f(zg);
        float h2new = sigm(zo) * tanh_f(cst2);
        if (g == 0) h2b[np][u] = h2new;
        __syncthreads();                                  // h2_t visible

        // ---- q + gumbel-softmax (redundant on all lanes) ----
        float part = wl0 * h2b[np][u0] + wl1 * h2b[np][u0 + 16];
        part += __shfl_xor(part, 1, 64);
        part += __shfl_xor(part, 2, 64);
        part += __shfl_xor(part, 4, 64);
        part += __shfl_xor(part, 8, 64);
        float qown = part + blc;
        float t1 = __shfl_xor(qown, 16, 64);
        float t2 = __shfl_xor(qown, 32, 64);
        float t3 = __shfl_xor(t1, 32, 64);
        float q0 = (g == 0) ? qown : (g == 1) ? t1 : (g == 2) ? t2 : t3;
        float q1 = (g == 0) ? t1 : (g == 1) ? qown : (g == 2) ? t3 : t2;
        float q2 = (g == 0) ? t2 : (g == 1) ? t3 : (g == 2) ? qown : t1;
        float q3 = (g == 0) ? t3 : (g == 1) ? t2 : (g == 2) ? t1 : qown;
        float l0  = (q0 + gt.x) * inv_tau;
        float l1_ = (q1 + gt.y) * inv_tau;
        float l2  = (q2 + gt.z) * inv_tau;
        float l3  = (q3 + gt.w) * inv_tau;
        float m = fmaxf(fmaxf(l0, l1_), fmaxf(l2, l3));
        float e0 = __expf(l0 - m), e1 = __expf(l1_ - m);
        float e2 = __expf(l2 - m), e3 = __expf(l3 - m);
        float inv = rcpf((e0 + e1) + (e2 + e3));
        y0 = e0 * inv; y1 = e1 * inv; y2 = e2 * inv; y3 = e3 * inv;

        if (tid == 0) *(float4*)(ob + (size_t)tg * CC) = make_float4(y0, y1, y2, y3);
    }

    // save carry state for next chunk
    const int lastnp = ((tc - 1) & 1) ^ 1;
    if (tid < HH) { st[tid] = h1b[lastnp][tid]; st[64 + tid] = h2b[lastnp][tid]; }
    if (g == 0)   { st[32 + u] = cst1; st[96 + u] = cst2; }
    if (tid == 0) { st[128] = y0; st[129] = y1; st[130] = y2; st[131] = y3; }
}

// ---------------- Fallback (verbatim R3 kernel, used only if ws too small) ----------
extern "C" __global__ void __launch_bounds__(128, 2)
lstm_opt_enc(const float* __restrict__ states, const float* __restrict__ taup,
             const float* __restrict__ gumbel, const float* __restrict__ w_ih0,
             const float* __restrict__ w_hh0, const float* __restrict__ b_ih0,
             const float* __restrict__ b_hh0, const float* __restrict__ w_ih1,
             const float* __restrict__ w_hh1, const float* __restrict__ b_ih1,
             const float* __restrict__ b_hh1, const float* __restrict__ w_lin,
             const float* __restrict__ b_lin, float* __restrict__ out)
{
    const int b   = blockIdx.x;
    const int tid = threadIdx.x;
    const int l   = tid & 63;
    const int wv  = tid >> 6;
    const int u0  = l & 15;
    const int g   = l >> 4;
    const int u   = wv * 16 + u0;
    const int r   = g * 32 + u;

    __shared__ __align__(16) float xb[2][DD];
    __shared__ __align__(16) float h1b[2][HH];
    __shared__ __align__(16) float h2b[2][HH];

    float wi0r[68], wh0r[HH], wi1r[HH], wh1r[HH];
#pragma unroll
    for (int k = 0; k < 68; ++k) wi0r[k] = w_ih0[r * 68 + k];
#pragma unroll
    for (int k = 0; k < HH; ++k) wh0r[k] = w_hh0[r * HH + k];
#pragma unroll
    for (int k = 0; k < HH; ++k) wi1r[k] = w_ih1[r * HH + k];
#pragma unroll
    for (int k = 0; k < HH; ++k) wh1r[k] = w_hh1[r * HH + k];
    const float bias0 = b_ih0[r] + b_hh0[r];
    const float bias1 = b_ih1[r] + b_hh1[r];
    const float inv_tau = rcpf(taup[0]);
    const float wl0 = w_lin[g * HH + u0];
    const float wl1 = w_lin[g * HH + u0 + 16];
    const float blc = b_lin[g];

    float cst1 = 0.f, cst2 = 0.f;
    float y0 = 1.f, y1 = 0.f, y2 = 0.f, y3 = 0.f;

    const float* __restrict__ sb = states + (size_t)b * TT * DD;
    float* __restrict__ ob = out + (size_t)b * TT * CC;

    float xr = 0.f;
    if (tid < DD) xr = sb[tid];
    if (tid < HH) { h1b[0][tid] = 0.f; h2b[0][tid] = 0.f; }
    if (tid < DD) { xb[0][tid] = xr; xr = sb[DD + tid]; }
    __syncthreads();

    for (int t = 0; t < TT; ++t) {
        const int p = t & 1, np = p ^ 1;
        if (tid < DD) { xb[np][tid] = xr; }
        const int tn = (t + 2 < TT) ? t + 2 : TT - 1;
        if (tid < DD) { xr = sb[tn * DD + tid]; }
        const float4 gt = *(const float4*)(gumbel + ((size_t)t * BB + b) * CC);

        float a0 = bias0, a1 = 0.f, a2 = 0.f, a3 = 0.f;
        const float4* xv = (const float4*)xb[p];
#pragma unroll
        for (int k = 0; k < 16; ++k) {
            float4 x4 = xv[k];
            a0 = fmaf(wi0r[4 * k + 0], x4.x, a0);
            a1 = fmaf(wi0r[4 * k + 1], x4.y, a1);
            a2 = fmaf(wi0r[4 * k + 2], x4.z, a2);
            a3 = fmaf(wi0r[4 * k + 3], x4.w, a3);
        }
        a0 = fmaf(wi0r[64], y0, a0);
        a1 = fmaf(wi0r[65], y1, a1);
        a2 = fmaf(wi0r[66], y2, a2);
        a3 = fmaf(wi0r[67], y3, a3);
        const float4* h1v = (const float4*)h1b[p];
#pragma unroll
        for (int k = 0; k < 8; ++k) {
            float4 h4 = h1v[k];
            a0 = fmaf(wh0r[4 * k + 0], h4.x, a0);
            a1 = fmaf(wh0r[4 * k + 1], h4.y, a1);
            a2 = fmaf(wh0r[4 * k + 2], h4.z, a2);
            a3 = fmaf(wh0r[4 * k + 3], h4.w, a3);
        }
        float z = (a0 + a1) + (a2 + a3);
        float v1  = __shfl_xor(z, 16, 64);
        float lo  = (g & 1) ? v1 : z;
        float hi  = (g & 1) ? z  : v1;
        float lo2 = __shfl_xor(lo, 32, 64);
        float hi2 = __shfl_xor(hi, 32, 64);
        float zi = (g < 2) ? lo  : lo2;
        float zf = (g < 2) ? hi  : hi2;
        float zg = (g < 2) ? lo2 : lo;
        float zo = (g < 2) ? hi2 : hi;
        cst1 = sigm(zf) * cst1 + sigm(zi) * tanh_f(zg);
        float h1new = sigm(zo) * tanh_f(cst1);
        if (g == 0) h1b[np][u] = h1new;
        __syncthreads();

        a0 = bias1; a1 = 0.f; a2 = 0.f; a3 = 0.f;
        const float4* h1n = (const float4*)h1b[np];
        const float4* h2v = (const float4*)h2b[p];
#pragma unroll
        for (int k = 0; k < 8; ++k) {
            float4 h4 = h1n[k];
            float4 g4 = h2v[k];
            a0 = fmaf(wi1r[4 * k + 0], h4.x, a0);
            a1 = fmaf(wi1r[4 * k + 1], h4.y, a1);
            a2 = fmaf(wi1r[4 * k + 2], h4.z, a2);
            a3 = fmaf(wi1r[4 * k + 3], h4.w, a3);
            a0 = fmaf(wh1r[4 * k + 0], g4.x, a0);
            a1 = fmaf(wh1r[4 * k + 1], g4.y, a1);
            a2 = fmaf(wh1r[4 * k + 2], g4.z, a2);
            a3 = fmaf(wh1r[4 * k + 3], g4.w, a3);
        }
        z = (a0 + a1) + (a2 + a3);
        v1  = __shfl_xor(z, 16, 64);
        lo  = (g & 1) ? v1 : z;
        hi  = (g & 1) ? z  : v1;
        lo2 = __shfl_xor(lo, 32, 64);
        hi2 = __shfl_xor(hi, 32, 64);
        zi = (g < 2) ? lo  : lo2;
        zf = (g < 2) ? hi  : hi2;
        zg = (g < 2) ? lo2 : lo;
        zo = (g < 2) ? hi2 : hi;
        cst2 = sigm(zf) * cst2 + sigm(zi) * tanh_f(zg);
        float h2new = sigm(zo) * tanh_f(cst2);
        if (g == 0) h2b[np][u] = h2new;
        __syncthreads();

        float part = wl0 * h2b[np][u0] + wl1 * h2b[np][u0 + 16];
        part += __shfl_xor(part, 1, 64);
        part += __shfl_xor(part, 2, 64);
        part += __shfl_xor(part, 4, 64);
        part += __shfl_xor(part, 8, 64);
        float qown = part + blc;
        float t1 = __shfl_xor(qown, 16, 64);
        float t2 = __shfl_xor(qown, 32, 64);
        float t3 = __shfl_xor(t1, 32, 64);
        float q0 = (g == 0) ? qown : (g == 1) ? t1 : (g == 2) ? t2 : t3;
        float q1 = (g == 0) ? t1 : (g == 1) ? qown : (g == 2) ? t3 : t2;
        float q2 = (g == 0) ? t2 : (g == 1) ? t3 : (g == 2) ? qown : t1;
        float q3 = (g == 0) ? t3 : (g == 1) ? t2 : (g == 2) ? t1 : qown;
        float l0  = (q0 + gt.x) * inv_tau;
        float l1_ = (q1 + gt.y) * inv_tau;
        float l2  = (q2 + gt.z) * inv_tau;
        float l3  = (q3 + gt.w) * inv_tau;
        float m = fmaxf(fmaxf(l0, l1_), fmaxf(l2, l3));
        float e0 = __expf(l0 - m), e1 = __expf(l1_ - m);
        float e2 = __expf(l2 - m), e3 = __expf(l3 - m);
        float inv = rcpf((e0 + e1) + (e2 + e3));
        y0 = e0 * inv; y1 = e1 * inv; y2 = e2 * inv; y3 = e3 * inv;

        if (tid == 0) *(float4*)(ob + (size_t)t * CC) = make_float4(y0, y1, y2, y3);
    }
}

extern "C" void kernel_launch(void* const* d_in, const int* in_sizes, int n_in,
                              void* d_out, int out_size, void* d_ws, size_t ws_size,
                              hipStream_t stream) {
    const float* states = (const float*)d_in[0];
    const float* tau    = (const float*)d_in[1];
    const float* gumbel = (const float*)d_in[2];
    const float* w_ih0  = (const float*)d_in[3];
    const float* w_hh0  = (const float*)d_in[4];
    const float* b_ih0  = (const float*)d_in[5];
    const float* b_hh0  = (const float*)d_in[6];
    const float* w_ih1  = (const float*)d_in[7];
    const float* w_hh1  = (const float*)d_in[8];
    const float* b_ih1  = (const float*)d_in[9];
    const float* b_hh1  = (const float*)d_in[10];
    const float* b_lin  = (const float*)d_in[12];
    const float* w_lin  = (const float*)d_in[11];
    float* out = (float*)d_out;

    // workspace budget: zx chunk [B][Tc][128] f32 + carry state [B][136] f32
    const long long state_bytes = (long long)BB * 136 * 4;
    long long avail = (long long)ws_size - state_bytes;
    long long Tcl = avail > 0 ? avail / ((long long)BB * 128 * 4) : 0;
    int Tc = (int)(Tcl > TT ? TT : Tcl);

    if (Tc < 8) {
        // not enough scratch: known-good single-kernel path
        hipLaunchKernelGGL(lstm_opt_enc, dim3(BB), dim3(128), 0, stream,
                           states, tau, gumbel, w_ih0, w_hh0, b_ih0, b_hh0,
                           w_ih1, w_hh1, b_ih1, b_hh1, w_lin, b_lin, out);
        return;
    }

    float* zx = (float*)d_ws;
    float* st = (float*)((char*)d_ws + (size_t)BB * Tc * 128 * 4);

    int done = 0, first = 1;
    while (done < TT) {
        int tc = (TT - done < Tc) ? (TT - done) : Tc;
        int tiles = (tc + 15) / 16;
        hipLaunchKernelGGL(zx_gemm, dim3(tiles, BB), dim3(128), 0, stream,
                           states, w_ih0, b_ih0, b_hh0, zx, done, tc, Tc);
        hipLaunchKernelGGL(lstm_rec, dim3(BB), dim3(128), 0, stream,
                           zx, tau, gumbel, w_ih0, w_hh0, w_ih1, w_hh1,
                           b_ih1, b_hh1, w_lin, b_lin, out, st, done, tc, Tc, first);
        first = 0;
        done += tc;
    }
}